// Round 3
// baseline (542.021 us; speedup 1.0000x reference)
//
#include <hip/hip_runtime.h>
#include <math.h>

namespace {

constexpr int NQ = 10;
constexpr int NL = 4;
constexpr float PI_F = 3.14159265358979323846f;

// ---------------------------------------------------------------------------
// GF(2) linear-algebra at compile time.
// State index j (10 bits): bit p has weight 2^p; wire w acts on bit p = 9-w.
// Storage index v = (lane<<4)|r. Invariant before layer l's gates:
//   s[v] = psi[M_l v],  M_l = F^{-l}
// where F is the composed per-layer CNOT chain: psi_out[j] = psi_in[F j].
// Gate on state bit p then pairs storage v with v ^ (F^l e_p), role (hi/lo)
// = parity(row_p(F^{-l}) & v). CNOTs themselves move NO data.
// ---------------------------------------------------------------------------
struct M10 { unsigned r[10]; };

constexpr M10 I10{{1u,2u,4u,8u,16u,32u,64u,128u,256u,512u}};
// F: b_k=a_k^a_{k+1} (k=0..7), b8=a8^a9^a0, b9=a9^a0  (CNOT chain
// (9,8)(8,7)...(1,0)(0,9) in amplitude-index form, composed).
constexpr M10 Fm{{0x003u,0x006u,0x00Cu,0x018u,0x030u,0x060u,0x0C0u,0x180u,0x301u,0x201u}};
// F^{-1}: a_k = b_k^...^b9 (k=0..8 suffix XORs), a9 = b0^...^b8.
constexpr M10 Fi{{0x3FFu,0x3FEu,0x3FCu,0x3F8u,0x3F0u,0x3E0u,0x3C0u,0x380u,0x300u,0x1FFu}};

constexpr M10 mmul(const M10& A, const M10& B) {
  M10 C{};
  for (int p = 0; p < 10; ++p) {
    unsigned v = 0;
    for (int q = 0; q < 10; ++q)
      if ((A.r[p] >> q) & 1u) v ^= B.r[q];
    C.r[p] = v;
  }
  return C;
}
constexpr bool meq(const M10& A, const M10& B) {
  for (int p = 0; p < 10; ++p) if (A.r[p] != B.r[p]) return false;
  return true;
}
static_assert(meq(mmul(Fm, Fi), I10), "F inverse wrong");

constexpr M10 mpow(const M10& A, int n) {
  M10 R = I10;
  for (int i = 0; i < n; ++i) R = mmul(R, A);
  return R;
}
// Gate mask for layer l, state bit p: column p of F^l.
constexpr unsigned gmask(int l, int p) {
  M10 Fl = mpow(Fm, l);
  unsigned m = 0;
  for (int q = 0; q < 10; ++q)
    if ((Fl.r[q] >> p) & 1u) m |= 1u << q;
  return m;
}
// Role row for layer l, state bit p: row p of F^{-l}.
constexpr unsigned grole(int l, int p) { return mpow(Fi, l).r[p]; }

constexpr M10 Fi4 = mpow(Fi, 4);  // measurement relabeling

// ---------------------------------------------------------------------------
// One fused single-qubit gate U (complex 2x2) applied under relabeling.
// MASK = storage-xor between pair partners; ROLE = parity row giving hi/lo.
// parity(ROLE & MASK) == 1 structurally, so partners always get opposite roles.
// ---------------------------------------------------------------------------
template<unsigned MASK, unsigned ROLE>
__device__ __forceinline__ void apply_gate(float (&re)[16], float (&im)[16],
    float u00r, float u00i, float u01r, float u01i,
    float u10r, float u10i, float u11r, float u11i, int lane) {
  constexpr int mlane = (int)((MASK >> 4) & 63u);
  constexpr int mreg  = (int)(MASK & 15u);
  constexpr int Rlane = (int)((ROLE >> 4) & 63u);
  constexpr int Rreg  = (int)(ROLE & 15u);
  // Runtime lane component of the role; reg component folds per unrolled r.
  const bool hl = (__popc(Rlane & lane) & 1) != 0;
  // Coefficient sets: index = reg-parity; set already folds in hl.
  // self coef for role h: h?u11:u00 ; partner coef: h?u10:u01
  float s0r = hl ? u11r : u00r, s0i = hl ? u11i : u00i;
  float q0r = hl ? u10r : u01r, q0i = hl ? u10i : u01i;
  float s1r = hl ? u00r : u11r, s1i = hl ? u00i : u11i;
  float q1r = hl ? u01r : u10r, q1i = hl ? u01i : u10i;

  if constexpr (mlane == 0) {
    constexpr int pivot = mreg & (-mreg);
#pragma unroll
    for (int r0 = 0; r0 < 16; ++r0) {
      if ((r0 & pivot) == 0) {
        const int r1 = r0 ^ mreg;
        const int pr0 = __popc(Rreg & r0) & 1;
        const int pr1 = __popc(Rreg & r1) & 1;   // = !pr0 here (mlane==0)
        float aSr = pr0 ? s1r : s0r, aSi = pr0 ? s1i : s0i;
        float aQr = pr0 ? q1r : q0r, aQi = pr0 ? q1i : q0i;
        float bSr = pr1 ? s1r : s0r, bSi = pr1 ? s1i : s0i;
        float bQr = pr1 ? q1r : q0r, bQi = pr1 ? q1i : q0i;
        float a0r = re[r0], a0i = im[r0], a1r = re[r1], a1i = im[r1];
        re[r0] = aSr * a0r - aSi * a0i + aQr * a1r - aQi * a1i;
        im[r0] = aSr * a0i + aSi * a0r + aQr * a1i + aQi * a1r;
        re[r1] = bSr * a1r - bSi * a1i + bQr * a0r - bQi * a0i;
        im[r1] = bSr * a1i + bSi * a1r + bQr * a0i + bQi * a0r;
      }
    }
  } else if constexpr (mreg == 0) {
#pragma unroll
    for (int r = 0; r < 16; ++r) {
      const int pr = __popc(Rreg & r) & 1;
      float aSr = pr ? s1r : s0r, aSi = pr ? s1i : s0i;
      float aQr = pr ? q1r : q0r, aQi = pr ? q1i : q0i;
      float pRe = __shfl_xor(re[r], mlane, 64);
      float pIm = __shfl_xor(im[r], mlane, 64);
      float oR = re[r], oI = im[r];
      re[r] = aSr * oR - aSi * oI + aQr * pRe - aQi * pIm;
      im[r] = aSr * oI + aSi * oR + aQr * pIm + aQi * pRe;
    }
  } else {
    // Partner of (lane, r) is (lane^mlane, r^mreg). Process reg-pairs together
    // so both shfl reads see pre-update values.
    constexpr int pivot = mreg & (-mreg);
#pragma unroll
    for (int r0 = 0; r0 < 16; ++r0) {
      if ((r0 & pivot) == 0) {
        const int r1 = r0 ^ mreg;
        const int pr0 = __popc(Rreg & r0) & 1;
        const int pr1 = __popc(Rreg & r1) & 1;   // may equal pr0 (flip via lane)
        float aSr = pr0 ? s1r : s0r, aSi = pr0 ? s1i : s0i;
        float aQr = pr0 ? q1r : q0r, aQi = pr0 ? q1i : q0i;
        float bSr = pr1 ? s1r : s0r, bSi = pr1 ? s1i : s0i;
        float bQr = pr1 ? q1r : q0r, bQi = pr1 ? q1i : q0i;
        float p0Re = __shfl_xor(re[r1], mlane, 64);
        float p0Im = __shfl_xor(im[r1], mlane, 64);
        float p1Re = __shfl_xor(re[r0], mlane, 64);
        float p1Im = __shfl_xor(im[r0], mlane, 64);
        float a0r = re[r0], a0i = im[r0], a1r = re[r1], a1i = im[r1];
        re[r0] = aSr * a0r - aSi * a0i + aQr * p0Re - aQi * p0Im;
        im[r0] = aSr * a0i + aSi * a0r + aQr * p0Im + aQi * p0Re;
        re[r1] = bSr * a1r - bSi * a1i + bQr * p1Re - bQi * p1Im;
        im[r1] = bSr * a1i + bSi * a1r + bQr * p1Im + bQi * p1Re;
      }
    }
  }
}

template<int L>
__device__ __forceinline__ void do_layer(float (&re)[16], float (&im)[16],
                                         const float4* wmat,
                                         float cxv, float sxv, int lane) {
#define FUSED(i) { \
    float4 wa = wmat[(L * NQ + (i)) * 2], wb = wmat[(L * NQ + (i)) * 2 + 1]; \
    float ca = __shfl(cxv, (i), 64), sa = __shfl(sxv, (i), 64); \
    float u00r = ca * wa.x + sa * wa.z, u00i = ca * wa.y + sa * wa.w; \
    float u01r = ca * wa.z - sa * wa.x, u01i = ca * wa.w - sa * wa.y; \
    float u10r = ca * wb.x + sa * wb.z, u10i = ca * wb.y + sa * wb.w; \
    float u11r = ca * wb.z - sa * wb.x, u11i = ca * wb.w - sa * wb.y; \
    apply_gate<gmask(L, 9 - (i)), grole(L, 9 - (i))>( \
        re, im, u00r, u00i, u01r, u01i, u10r, u10i, u11r, u11i, lane); }
  FUSED(0) FUSED(1) FUSED(2) FUSED(3) FUSED(4)
  FUSED(5) FUSED(6) FUSED(7) FUSED(8) FUSED(9)
#undef FUSED
  // CNOT chain: absorbed into the relabeling (masks of layer L+1) — no data movement.
}

__global__ __launch_bounds__(256) void qsim(const float* __restrict__ x,
                                            const float* __restrict__ w,
                                            float* __restrict__ out, int batch) {
  // Batch-shared fused weight matrices W = RZ(w2)*RY(w1)*RZ(w0), one complex
  // 2x2 per (layer, wire): [w00, w01 | w10, w11] as two float4.
  __shared__ float4 wmat[NL * NQ * 2];
  int tid = threadIdx.x;
  if (tid < NL * NQ) {
    const float* wp = &w[tid * 3];
    float t0 = 0.5f * wp[0], t1 = 0.5f * wp[1], t2 = 0.5f * wp[2];
    float c1, s1; sincosf(t1, &s1, &c1);
    float cA, sA; sincosf(t0 + t2, &sA, &cA);
    float cB, sB; sincosf(t0 - t2, &sB, &cB);
    wmat[tid * 2]     = make_float4(c1 * cA, -c1 * sA, -s1 * cB, -s1 * sB);
    wmat[tid * 2 + 1] = make_float4(s1 * cB, -s1 * sB,  c1 * cA,  c1 * sA);
  }
  __syncthreads();

  int lane = tid & 63;
  int b = blockIdx.x * 4 + (tid >> 6);
  if (b >= batch) return;

  // Per-element data angles: lanes 0..9 each compute one sincos, broadcast at use.
  float cxv = 1.0f, sxv = 0.0f;
  if (lane < NQ) {
    float th = tanhf(x[b * NQ + lane]) * PI_F;
    sincosf(0.5f * th, &sxv, &cxv);
  }

  float re[16], im[16];
#pragma unroll
  for (int r = 0; r < 16; ++r) { re[r] = 0.0f; im[r] = 0.0f; }
  if (lane == 0) re[0] = 1.0f;  // M_0 = I, so s = psi initially

  do_layer<0>(re, im, wmat, cxv, sxv, lane);
  do_layer<1>(re, im, wmat, cxv, sxv, lane);
  do_layer<2>(re, im, wmat, cxv, sxv, lane);
  do_layer<3>(re, im, wmat, cxv, sxv, lane);

  // Measurement under final relabeling M = F^{-4}:
  // out[b][q] = sum_v |s[v]|^2 * (-1)^parity(Fi4.row[9-q] & v)
  float prob[16];
#pragma unroll
  for (int r = 0; r < 16; ++r) prob[r] = re[r] * re[r] + im[r] * im[r];

  float part[10];
#pragma unroll
  for (int q = 0; q < NQ; ++q) {
    const unsigned ROW = Fi4.r[9 - q];
    const int sl = __popc((int)((ROW >> 4) & 63u) & lane) & 1;
    float acc = 0.0f;
#pragma unroll
    for (int r = 0; r < 16; ++r)
      acc += ((__popc((int)(ROW & 15u) & r) & 1) ? -prob[r] : prob[r]);
    part[q] = sl ? -acc : acc;
  }
#pragma unroll
  for (int q = 0; q < NQ; ++q) {
#pragma unroll
    for (int m = 1; m < 64; m <<= 1)
      part[q] += __shfl_xor(part[q], m, 64);
  }

  if (lane == 0) {
#pragma unroll
    for (int q = 0; q < NQ; ++q)
      out[b * NQ + q] = part[q];
  }
}

}  // namespace

extern "C" void kernel_launch(void* const* d_in, const int* in_sizes, int n_in,
                              void* d_out, int out_size, void* d_ws, size_t ws_size,
                              hipStream_t stream) {
  const float* x = (const float*)d_in[0];
  const float* w = (const float*)d_in[1];
  float* out = (float*)d_out;
  int batch = in_sizes[0] / NQ;
  int blocks = (batch + 3) / 4;  // 4 waves/block, 1 batch element per wave
  qsim<<<blocks, 256, 0, stream>>>(x, w, out, batch);
}

// Round 5
// 327.835 us; speedup vs baseline: 1.6533x; 1.6533x over previous
//
#include <hip/hip_runtime.h>
#include <math.h>

namespace {

constexpr int NQ = 10;
constexpr int NL = 4;
constexpr float PI_F = 3.14159265358979323846f;

// State: per-wave 1024 complex amps. Lane holds amps with idx = (lane<<4)|r.
// Wire w acts on bit p = 9 - w. p<4: in-register pairs; p>=4: lane-bit via shfl_xor.
//
// Fusion: per (layer, wire) the reference applies RY(data)*RZ(w0)*RY(w1)*RZ(w2)
// (gates on different wires commute -> per-wire subsequence contiguous).
// W = RZ(w2)*RY(w1)*RZ(w0) is batch-shared, precomputed into LDS; per element
// U = W * RY(a) is ONE complex 2x2 gate.
//
// VGPR discipline (R2 post-mortem): NO temp arrays inside the runtime layer
// loop — register CNOTs are in-place pairwise swaps, keeping VGPR low.
// R4 post-mortem: readlane on float MUST be bit-cast (i32 builtin).

__device__ __forceinline__ float readlane_f(float v, int lane_const) {
  return __int_as_float(__builtin_amdgcn_readlane(__float_as_int(v), lane_const));
}

template<int P>
__device__ __forceinline__ void apply_u(float (&re)[16], float (&im)[16],
                                        float u00r, float u00i, float u01r, float u01i,
                                        float u10r, float u10i, float u11r, float u11i,
                                        int lane) {
  if constexpr (P < 4) {
    constexpr int bit = 1 << P;
#pragma unroll
    for (int r = 0; r < 16; ++r) {
      if ((r & bit) == 0) {
        int r1 = r | bit;
        float a0r = re[r], a0i = im[r], a1r = re[r1], a1i = im[r1];
        re[r]  = u00r * a0r - u00i * a0i + u01r * a1r - u01i * a1i;
        im[r]  = u00r * a0i + u00i * a0r + u01r * a1i + u01i * a1r;
        re[r1] = u10r * a0r - u10i * a0i + u11r * a1r - u11i * a1i;
        im[r1] = u10r * a0i + u10i * a0r + u11r * a1i + u11i * a1r;
      }
    }
  } else {
    constexpr int mask = 1 << (P - 4);
    bool hi = (lane & mask) != 0;
    // own-coef = hi ? u11 : u00 ; partner-coef = hi ? u10 : u01
    float cAr = hi ? u11r : u00r, cAi = hi ? u11i : u00i;
    float cBr = hi ? u10r : u01r, cBi = hi ? u10i : u01i;
#pragma unroll
    for (int r = 0; r < 16; ++r) {
      float pr = __shfl_xor(re[r], mask, 64);
      float pi = __shfl_xor(im[r], mask, 64);
      float orr = re[r], oi = im[r];
      re[r] = cAr * orr - cAi * oi + cBr * pr - cBi * pi;
      im[r] = cAr * oi + cAi * orr + cBr * pi + cBi * pr;
    }
  }
}

__global__ __launch_bounds__(256) void qsim(const float* __restrict__ x,
                                            const float* __restrict__ w,
                                            float* __restrict__ out, int batch) {
  // Batch-shared fused weight matrices W = RZ(w2)*RY(w1)*RZ(w0), one complex
  // 2x2 per (layer, wire): [w00, w01 | w10, w11] as two float4.
  __shared__ float4 wmat[NL * NQ * 2];
  int tid = threadIdx.x;
  if (tid < NL * NQ) {
    const float* wp = &w[tid * 3];
    float t0 = 0.5f * wp[0], t1 = 0.5f * wp[1], t2 = 0.5f * wp[2];
    float c1, s1; sincosf(t1, &s1, &c1);
    float cA, sA; sincosf(t0 + t2, &sA, &cA);
    float cB, sB; sincosf(t0 - t2, &sB, &cB);
    // w00 = c1*e^{-iA}; w01 = -s1*e^{+iB}; w10 = s1*e^{-iB}; w11 = c1*e^{+iA}
    wmat[tid * 2]     = make_float4(c1 * cA, -c1 * sA, -s1 * cB, -s1 * sB);
    wmat[tid * 2 + 1] = make_float4(s1 * cB, -s1 * sB,  c1 * cA,  c1 * sA);
  }
  __syncthreads();

  int lane = tid & 63;
  int b = blockIdx.x * 4 + (tid >> 6);
  if (b >= batch) return;

  // Per-element data angles: lanes 0..9 each compute one sincos; broadcast
  // at use via bit-cast readlane (wave-uniform -> SGPR, no DS traffic).
  float cxv = 1.0f, sxv = 0.0f;
  if (lane < NQ) {
    float th = tanhf(x[b * NQ + lane]) * PI_F;
    sincosf(0.5f * th, &sxv, &cxv);
  }

  // Composed lane-permutation for the 5 lane-lane CNOTs (state bits (9,8)..(5,4)
  // = lane bits (5,4)..(1,0), applied in that order). new[l] = old[srcl].
  int srcl;
  {
    int t = lane;
    t ^= (t >> 1) & 1;          // last gate  C(1,0)
    t ^= ((t >> 2) & 1) << 1;   //            C(2,1)
    t ^= ((t >> 3) & 1) << 2;   //            C(3,2)
    t ^= ((t >> 4) & 1) << 3;   //            C(4,3)
    t ^= ((t >> 5) & 1) << 4;   // first gate C(5,4)
    srcl = t;
  }

  float re[16], im[16];
#pragma unroll
  for (int r = 0; r < 16; ++r) { re[r] = 0.0f; im[r] = 0.0f; }
  if (lane == 0) re[0] = 1.0f;

  for (int l = 0; l < NL; ++l) {
#define FUSED(i) { \
    float4 wa = wmat[(l * NQ + (i)) * 2], wb = wmat[(l * NQ + (i)) * 2 + 1]; \
    float ca = readlane_f(cxv, (i)); \
    float sa = readlane_f(sxv, (i)); \
    float u00r = ca * wa.x + sa * wa.z, u00i = ca * wa.y + sa * wa.w; \
    float u01r = ca * wa.z - sa * wa.x, u01i = ca * wa.w - sa * wa.y; \
    float u10r = ca * wb.x + sa * wb.z, u10i = ca * wb.y + sa * wb.w; \
    float u11r = ca * wb.z - sa * wb.x, u11i = ca * wb.w - sa * wb.y; \
    apply_u<9 - (i)>(re, im, u00r, u00i, u01r, u01i, u10r, u10i, u11r, u11i, lane); }
    FUSED(0) FUSED(1) FUSED(2) FUSED(3) FUSED(4)
    FUSED(5) FUSED(6) FUSED(7) FUSED(8) FUSED(9)
#undef FUSED

    // --- CNOT chain: (9,8)(8,7)(7,6)(6,5)(5,4) | (4,3) | (3,2)(2,1)(1,0) | (0,9)
    // 1) five lane-lane CNOTs as ONE composed bpermute
#pragma unroll
    for (int r = 0; r < 16; ++r) {
      re[r] = __shfl(re[r], srcl, 64);
      im[r] = __shfl(im[r], srcl, 64);
    }
    // 2) (4,3): ctrl = lane bit 0, target = reg bit 3 (in-place cndmask swap)
    {
      bool ctrl = (lane & 1) != 0;
#pragma unroll
      for (int r = 0; r < 8; ++r) {
        int r1 = r | 8;
        float t0r = re[r], t0i = im[r], t1r = re[r1], t1i = im[r1];
        re[r]  = ctrl ? t1r : t0r;  im[r]  = ctrl ? t1i : t0i;
        re[r1] = ctrl ? t0r : t1r;  im[r1] = ctrl ? t0i : t1i;
      }
    }
    // 3) (3,2)(2,1)(1,0): sequential in-place pair swaps (no temps)
    //    (3,2): swap (8,12)(9,13)(10,14)(11,15)
#pragma unroll
    for (int r = 8; r < 12; ++r) {
      float t = re[r]; re[r] = re[r | 4]; re[r | 4] = t;
      t = im[r]; im[r] = im[r | 4]; im[r | 4] = t;
    }
    //    (2,1): swap (4,6)(5,7)(12,14)(13,15)
    {
      const int rs[4] = {4, 5, 12, 13};
#pragma unroll
      for (int k = 0; k < 4; ++k) {
        int r = rs[k];
        float t = re[r]; re[r] = re[r | 2]; re[r | 2] = t;
        t = im[r]; im[r] = im[r | 2]; im[r | 2] = t;
      }
    }
    //    (1,0): swap (2,3)(6,7)(10,11)(14,15)
#pragma unroll
    for (int r = 2; r < 16; r += 4) {
      float t = re[r]; re[r] = re[r | 1]; re[r | 1] = t;
      t = im[r]; im[r] = im[r | 1]; im[r | 1] = t;
    }
    // 4) (0,9): ctrl = reg bit 0, target = lane bit 5 -> full exchange on odd r
#pragma unroll
    for (int r = 1; r < 16; r += 2) {
      re[r] = __shfl_xor(re[r], 32, 64);
      im[r] = __shfl_xor(im[r], 32, 64);
    }
  }

  // Measurement: out[b][q] = sum_idx prob[idx] * (bit(9-q) ? -1 : +1)
  float prob[16];
  float total = 0.0f;
#pragma unroll
  for (int r = 0; r < 16; ++r) {
    prob[r] = re[r] * re[r] + im[r] * im[r];
    total += prob[r];
  }
  float part[10];
#pragma unroll
  for (int p = 0; p < 4; ++p) {
    float acc = 0.0f;
#pragma unroll
    for (int r = 0; r < 16; ++r)
      acc += (r & (1 << p)) ? -prob[r] : prob[r];
    part[p] = acc;
  }
#pragma unroll
  for (int p = 4; p < 10; ++p)
    part[p] = (lane & (1 << (p - 4))) ? -total : total;

#pragma unroll
  for (int p = 0; p < 10; ++p) {
#pragma unroll
    for (int m = 1; m < 64; m <<= 1)
      part[p] += __shfl_xor(part[p], m, 64);
  }

  if (lane == 0) {
#pragma unroll
    for (int q = 0; q < NQ; ++q)
      out[b * NQ + q] = part[9 - q];
  }
}

}  // namespace

extern "C" void kernel_launch(void* const* d_in, const int* in_sizes, int n_in,
                              void* d_out, int out_size, void* d_ws, size_t ws_size,
                              hipStream_t stream) {
  const float* x = (const float*)d_in[0];
  const float* w = (const float*)d_in[1];
  float* out = (float*)d_out;
  int batch = in_sizes[0] / NQ;
  int blocks = (batch + 3) / 4;  // 4 waves/block, 1 batch element per wave
  qsim<<<blocks, 256, 0, stream>>>(x, w, out, batch);
}

// Round 6
// 243.042 us; speedup vs baseline: 2.2302x; 1.3489x over previous
//
#include <hip/hip_runtime.h>
#include <math.h>

namespace {

constexpr int NQ = 10;
constexpr int NL = 4;
constexpr float PI_F = 3.14159265358979323846f;

// Two batch elements per thread, packed as float2 (x = elem A, y = elem B).
// All gate arithmetic is element-wise on the packed pair -> clang lowers
// <2 x float> mul/add/fma to v_pk_mul_f32 / v_pk_fma_f32 on gfx950, halving
// VALU instructions per batch element.
//
// State: per-wave 1024 complex amp-pairs. Lane holds idx = (lane<<4)|r.
// Wire w acts on bit p = 9 - w. p<4: in-register pairs; p>=4: shfl_xor.
// Fused per (layer,wire): U = RZ(w2)*RY(w1)*RZ(w0) * RY(a) — one 2x2 gate.

typedef float v2 __attribute__((ext_vector_type(2)));

__device__ __forceinline__ float readlane_f(float v, int lane_const) {
  return __int_as_float(__builtin_amdgcn_readlane(__float_as_int(v), lane_const));
}

__device__ __forceinline__ v2 shfl_xor_v2(v2 v, int mask) {
  v2 r;
  r.x = __shfl_xor(v.x, mask, 64);
  r.y = __shfl_xor(v.y, mask, 64);
  return r;
}
__device__ __forceinline__ v2 shfl_v2(v2 v, int src) {
  v2 r;
  r.x = __shfl(v.x, src, 64);
  r.y = __shfl(v.y, src, 64);
  return r;
}

template<int P>
__device__ __forceinline__ void apply_u(v2 (&re)[16], v2 (&im)[16],
                                        v2 u00r, v2 u00i, v2 u01r, v2 u01i,
                                        v2 u10r, v2 u10i, v2 u11r, v2 u11i,
                                        int lane) {
  if constexpr (P < 4) {
    constexpr int bit = 1 << P;
#pragma unroll
    for (int r = 0; r < 16; ++r) {
      if ((r & bit) == 0) {
        int r1 = r | bit;
        v2 a0r = re[r], a0i = im[r], a1r = re[r1], a1i = im[r1];
        re[r]  = u00r * a0r - u00i * a0i + u01r * a1r - u01i * a1i;
        im[r]  = u00r * a0i + u00i * a0r + u01r * a1i + u01i * a1r;
        re[r1] = u10r * a0r - u10i * a0i + u11r * a1r - u11i * a1i;
        im[r1] = u10r * a0i + u10i * a0r + u11r * a1i + u11i * a1r;
      }
    }
  } else {
    constexpr int mask = 1 << (P - 4);
    bool hi = (lane & mask) != 0;
    // own-coef = hi ? u11 : u00 ; partner-coef = hi ? u10 : u01
    v2 cAr = hi ? u11r : u00r, cAi = hi ? u11i : u00i;
    v2 cBr = hi ? u10r : u01r, cBi = hi ? u10i : u01i;
#pragma unroll
    for (int r = 0; r < 16; ++r) {
      v2 pr = shfl_xor_v2(re[r], mask);
      v2 pi = shfl_xor_v2(im[r], mask);
      v2 orr = re[r], oi = im[r];
      re[r] = cAr * orr - cAi * oi + cBr * pr - cBi * pi;
      im[r] = cAr * oi + cAi * orr + cBr * pi + cBi * pr;
    }
  }
}

__global__ __launch_bounds__(256) void qsim(const float* __restrict__ x,
                                            const float* __restrict__ w,
                                            float* __restrict__ out, int batch) {
  // Batch-shared fused weight matrices W = RZ(w2)*RY(w1)*RZ(w0), one complex
  // 2x2 per (layer, wire): [w00, w01 | w10, w11] as two float4.
  __shared__ float4 wmat[NL * NQ * 2];
  int tid = threadIdx.x;
  if (tid < NL * NQ) {
    const float* wp = &w[tid * 3];
    float t0 = 0.5f * wp[0], t1 = 0.5f * wp[1], t2 = 0.5f * wp[2];
    float c1, s1; sincosf(t1, &s1, &c1);
    float cA, sA; sincosf(t0 + t2, &sA, &cA);
    float cB, sB; sincosf(t0 - t2, &sB, &cB);
    // w00 = c1*e^{-iA}; w01 = -s1*e^{+iB}; w10 = s1*e^{-iB}; w11 = c1*e^{+iA}
    wmat[tid * 2]     = make_float4(c1 * cA, -c1 * sA, -s1 * cB, -s1 * sB);
    wmat[tid * 2 + 1] = make_float4(s1 * cB, -s1 * sB,  c1 * cA,  c1 * sA);
  }
  __syncthreads();

  int lane = tid & 63;
  int pairIdx = blockIdx.x * 4 + (tid >> 6);   // one wave = 2 batch elements
  int bA = pairIdx * 2;
  if (bA >= batch) return;
  int bB = bA + 1;

  // Per-element data angles for BOTH packed elements: lanes 0..9 compute
  // sincos; broadcast at use via bit-cast readlane (wave-uniform -> SGPR).
  float cxA = 1.0f, sxA = 0.0f, cxB = 1.0f, sxB = 0.0f;
  if (lane < NQ) {
    float thA = tanhf(x[bA * NQ + lane]) * PI_F;
    sincosf(0.5f * thA, &sxA, &cxA);
    float thB = tanhf(x[bB * NQ + lane]) * PI_F;
    sincosf(0.5f * thB, &sxB, &cxB);
  }

  // Composed lane-permutation for the 5 lane-lane CNOTs (state bits (9,8)..(5,4)
  // = lane bits (5,4)..(1,0), applied in that order). new[l] = old[srcl].
  int srcl;
  {
    int t = lane;
    t ^= (t >> 1) & 1;          // last gate  C(1,0)
    t ^= ((t >> 2) & 1) << 1;   //            C(2,1)
    t ^= ((t >> 3) & 1) << 2;   //            C(3,2)
    t ^= ((t >> 4) & 1) << 3;   //            C(4,3)
    t ^= ((t >> 5) & 1) << 4;   // first gate C(5,4)
    srcl = t;
  }

  v2 re[16], im[16];
#pragma unroll
  for (int r = 0; r < 16; ++r) { re[r] = (v2)(0.0f); im[r] = (v2)(0.0f); }
  if (lane == 0) re[0] = (v2)(1.0f);

  for (int l = 0; l < NL; ++l) {
#define FUSED(i) { \
    float4 wa = wmat[(l * NQ + (i)) * 2], wb = wmat[(l * NQ + (i)) * 2 + 1]; \
    v2 ca, sa; \
    ca.x = readlane_f(cxA, (i)); ca.y = readlane_f(cxB, (i)); \
    sa.x = readlane_f(sxA, (i)); sa.y = readlane_f(sxB, (i)); \
    v2 u00r = ca * wa.x + sa * wa.z, u00i = ca * wa.y + sa * wa.w; \
    v2 u01r = ca * wa.z - sa * wa.x, u01i = ca * wa.w - sa * wa.y; \
    v2 u10r = ca * wb.x + sa * wb.z, u10i = ca * wb.y + sa * wb.w; \
    v2 u11r = ca * wb.z - sa * wb.x, u11i = ca * wb.w - sa * wb.y; \
    apply_u<9 - (i)>(re, im, u00r, u00i, u01r, u01i, u10r, u10i, u11r, u11i, lane); }
    FUSED(0) FUSED(1) FUSED(2) FUSED(3) FUSED(4)
    FUSED(5) FUSED(6) FUSED(7) FUSED(8) FUSED(9)
#undef FUSED

    // --- CNOT chain: (9,8)(8,7)(7,6)(6,5)(5,4) | (4,3) | (3,2)(2,1)(1,0) | (0,9)
    // 1) five lane-lane CNOTs as ONE composed bpermute
#pragma unroll
    for (int r = 0; r < 16; ++r) {
      re[r] = shfl_v2(re[r], srcl);
      im[r] = shfl_v2(im[r], srcl);
    }
    // 2) (4,3): ctrl = lane bit 0, target = reg bit 3 (in-place cndmask swap)
    {
      bool ctrl = (lane & 1) != 0;
#pragma unroll
      for (int r = 0; r < 8; ++r) {
        int r1 = r | 8;
        v2 t0r = re[r], t0i = im[r], t1r = re[r1], t1i = im[r1];
        re[r]  = ctrl ? t1r : t0r;  im[r]  = ctrl ? t1i : t0i;
        re[r1] = ctrl ? t0r : t1r;  im[r1] = ctrl ? t0i : t1i;
      }
    }
    // 3) (3,2)(2,1)(1,0): sequential in-place pair swaps (no temps)
    //    (3,2): swap (8,12)(9,13)(10,14)(11,15)
#pragma unroll
    for (int r = 8; r < 12; ++r) {
      v2 t = re[r]; re[r] = re[r | 4]; re[r | 4] = t;
      t = im[r]; im[r] = im[r | 4]; im[r | 4] = t;
    }
    //    (2,1): swap (4,6)(5,7)(12,14)(13,15)
    {
      const int rs[4] = {4, 5, 12, 13};
#pragma unroll
      for (int k = 0; k < 4; ++k) {
        int r = rs[k];
        v2 t = re[r]; re[r] = re[r | 2]; re[r | 2] = t;
        t = im[r]; im[r] = im[r | 2]; im[r | 2] = t;
      }
    }
    //    (1,0): swap (2,3)(6,7)(10,11)(14,15)
#pragma unroll
    for (int r = 2; r < 16; r += 4) {
      v2 t = re[r]; re[r] = re[r | 1]; re[r | 1] = t;
      t = im[r]; im[r] = im[r | 1]; im[r | 1] = t;
    }
    // 4) (0,9): ctrl = reg bit 0, target = lane bit 5 -> full exchange on odd r
#pragma unroll
    for (int r = 1; r < 16; r += 2) {
      re[r] = shfl_xor_v2(re[r], 32);
      im[r] = shfl_xor_v2(im[r], 32);
    }
  }

  // Measurement: out[b][q] = sum_idx prob[idx] * (bit(9-q) ? -1 : +1)
  v2 prob[16];
  v2 total = (v2)(0.0f);
#pragma unroll
  for (int r = 0; r < 16; ++r) {
    prob[r] = re[r] * re[r] + im[r] * im[r];
    total += prob[r];
  }
  v2 part[10];
#pragma unroll
  for (int p = 0; p < 4; ++p) {
    v2 acc = (v2)(0.0f);
#pragma unroll
    for (int r = 0; r < 16; ++r)
      acc += (r & (1 << p)) ? -prob[r] : prob[r];
    part[p] = acc;
  }
#pragma unroll
  for (int p = 4; p < 10; ++p)
    part[p] = (lane & (1 << (p - 4))) ? -total : total;

#pragma unroll
  for (int p = 0; p < 10; ++p) {
#pragma unroll
    for (int m = 1; m < 64; m <<= 1)
      part[p] += shfl_xor_v2(part[p], m);
  }

  if (lane == 0) {
#pragma unroll
    for (int q = 0; q < NQ; ++q) {
      out[bA * NQ + q] = part[9 - q].x;
      out[bB * NQ + q] = part[9 - q].y;
    }
  }
}

}  // namespace

extern "C" void kernel_launch(void* const* d_in, const int* in_sizes, int n_in,
                              void* d_out, int out_size, void* d_ws, size_t ws_size,
                              hipStream_t stream) {
  const float* x = (const float*)d_in[0];
  const float* w = (const float*)d_in[1];
  float* out = (float*)d_out;
  int batch = in_sizes[0] / NQ;
  int pairs = (batch + 1) / 2;
  int blocks = (pairs + 3) / 4;  // 4 waves/block, 2 batch elements per wave
  qsim<<<blocks, 256, 0, stream>>>(x, w, out, batch);
}

// Round 7
// 242.283 us; speedup vs baseline: 2.2371x; 1.0031x over previous
//
#include <hip/hip_runtime.h>
#include <math.h>

namespace {

constexpr int NQ = 10;
constexpr int NL = 4;
constexpr float PI_F = 3.14159265358979323846f;

// One batch element per wave. Each amp's (re,im) packed in ONE float2 ->
// state = 16 v2 = 32 VGPRs. Complex mul via v_pk_fma_f32 with op_sel/neg_lo
// (2 pk instructions per complex mul-add, no component swizzles).
// __launch_bounds__(256,8) caps VGPR at 64 -> 8 waves/SIMD (past the m69
// occupancy cliff at 64).
//
// State: lane holds amps idx = (lane<<4)|r. Wire w acts on state bit p=9-w.
// p<4: in-register pairs; p>=4: lane-bit exchange via shfl_xor.
// Fused per (layer,wire): U = RZ(w2)*RY(w1)*RZ(w0) * RY(a) — one 2x2 gate.

typedef float v2 __attribute__((ext_vector_type(2)));

__device__ __forceinline__ float readlane_f(float v, int lane_const) {
  return __int_as_float(__builtin_amdgcn_readlane(__float_as_int(v), lane_const));
}

// d = u (*) a   (complex multiply; u,a packed {re,im})
__device__ __forceinline__ v2 cmul(v2 u, v2 a) {
  v2 d;
  asm("v_pk_mul_f32 %0, %1, %2 op_sel:[0,0] op_sel_hi:[0,1]\n\t"
      "v_pk_fma_f32 %0, %1, %2, %0 op_sel:[1,1,0] op_sel_hi:[1,0,1] neg_lo:[1,0,0]"
      : "=&v"(d) : "v"(u), "v"(a));
  return d;
}
// d = acc + u (*) a
__device__ __forceinline__ v2 cfma(v2 u, v2 a, v2 acc) {
  v2 d;
  asm("v_pk_fma_f32 %0, %1, %2, %3 op_sel:[0,0,0] op_sel_hi:[0,1,1]\n\t"
      "v_pk_fma_f32 %0, %1, %2, %0 op_sel:[1,1,0] op_sel_hi:[1,0,1] neg_lo:[1,0,0]"
      : "=&v"(d) : "v"(u), "v"(a), "v"(acc));
  return d;
}

__device__ __forceinline__ v2 shfl_xor_v2(v2 v, int mask) {
  v2 r;
  r.x = __shfl_xor(v.x, mask, 64);
  r.y = __shfl_xor(v.y, mask, 64);
  return r;
}

template<int P>
__device__ __forceinline__ void apply_u(v2 (&s)[16],
                                        v2 u00, v2 u01, v2 u10, v2 u11,
                                        int lane) {
  if constexpr (P < 4) {
    constexpr int bit = 1 << P;
#pragma unroll
    for (int r = 0; r < 16; ++r) {
      if ((r & bit) == 0) {
        int r1 = r | bit;
        v2 a0 = s[r], a1 = s[r1];
        s[r]  = cfma(u01, a1, cmul(u00, a0));
        s[r1] = cfma(u11, a1, cmul(u10, a0));
      }
    }
  } else {
    constexpr int mask = 1 << (P - 4);
    bool hi = (lane & mask) != 0;
    v2 cA = hi ? u11 : u00;   // own coefficient
    v2 cB = hi ? u10 : u01;   // partner coefficient
#pragma unroll
    for (int r = 0; r < 16; ++r) {
      v2 p = shfl_xor_v2(s[r], mask);
      s[r] = cfma(cB, p, cmul(cA, s[r]));
    }
  }
}

__global__ __launch_bounds__(256, 8) void qsim(const float* __restrict__ x,
                                               const float* __restrict__ w,
                                               float* __restrict__ out, int batch) {
  // Batch-shared fused weight matrices W = RZ(w2)*RY(w1)*RZ(w0), one complex
  // 2x2 per (layer, wire): [w00, w01 | w10, w11] as two float4.
  __shared__ float4 wmat[NL * NQ * 2];
  int tid = threadIdx.x;
  if (tid < NL * NQ) {
    const float* wp = &w[tid * 3];
    float t0 = 0.5f * wp[0], t1 = 0.5f * wp[1], t2 = 0.5f * wp[2];
    float c1, s1; sincosf(t1, &s1, &c1);
    float cA, sA; sincosf(t0 + t2, &sA, &cA);
    float cB, sB; sincosf(t0 - t2, &sB, &cB);
    // w00 = c1*e^{-iA}; w01 = -s1*e^{+iB}; w10 = s1*e^{-iB}; w11 = c1*e^{+iA}
    wmat[tid * 2]     = make_float4(c1 * cA, -c1 * sA, -s1 * cB, -s1 * sB);
    wmat[tid * 2 + 1] = make_float4(s1 * cB, -s1 * sB,  c1 * cA,  c1 * sA);
  }
  __syncthreads();

  int lane = tid & 63;
  int b = blockIdx.x * 4 + (tid >> 6);
  if (b >= batch) return;

  // Per-element data angles: lanes 0..9 compute sincos; broadcast at use via
  // bit-cast readlane (wave-uniform -> SGPR).
  float cxv = 1.0f, sxv = 0.0f;
  if (lane < NQ) {
    float th = tanhf(x[b * NQ + lane]) * PI_F;
    sincosf(0.5f * th, &sxv, &cxv);
  }

  // Composed lane-permutation for the 5 lane-lane CNOTs (state bits (9,8)..(5,4)
  // = lane bits (5,4)..(1,0), applied in that order). new[l] = old[srcl].
  int srcl4;
  {
    int t = lane;
    t ^= (t >> 1) & 1;          // last gate  C(1,0)
    t ^= ((t >> 2) & 1) << 1;   //            C(2,1)
    t ^= ((t >> 3) & 1) << 2;   //            C(3,2)
    t ^= ((t >> 4) & 1) << 3;   //            C(4,3)
    t ^= ((t >> 5) & 1) << 4;   // first gate C(5,4)
    srcl4 = t << 2;             // byte address for ds_bpermute
  }

  v2 s[16];
#pragma unroll
  for (int r = 0; r < 16; ++r) s[r] = (v2)(0.0f);
  if (lane == 0) s[0].x = 1.0f;

  for (int l = 0; l < NL; ++l) {
#define FUSED(i) { \
    float4 wa = wmat[(l * NQ + (i)) * 2], wb = wmat[(l * NQ + (i)) * 2 + 1]; \
    float ca = readlane_f(cxv, (i)); \
    float sa = readlane_f(sxv, (i)); \
    v2 wa0 = {wa.x, wa.y}, wa1 = {wa.z, wa.w}; \
    v2 wb0 = {wb.x, wb.y}, wb1 = {wb.z, wb.w}; \
    v2 u00 = ca * wa0 + sa * wa1, u01 = ca * wa1 - sa * wa0; \
    v2 u10 = ca * wb0 + sa * wb1, u11 = ca * wb1 - sa * wb0; \
    apply_u<9 - (i)>(s, u00, u01, u10, u11, lane); }
    FUSED(0) FUSED(1) FUSED(2) FUSED(3) FUSED(4)
    FUSED(5) FUSED(6) FUSED(7) FUSED(8) FUSED(9)
#undef FUSED

    // --- CNOT chain: (9,8)(8,7)(7,6)(6,5)(5,4) | (4,3) | (3,2)(2,1)(1,0) | (0,9)
    // 1) five lane-lane CNOTs as ONE composed bpermute
#pragma unroll
    for (int r = 0; r < 16; ++r) {
      s[r].x = __int_as_float(__builtin_amdgcn_ds_bpermute(srcl4, __float_as_int(s[r].x)));
      s[r].y = __int_as_float(__builtin_amdgcn_ds_bpermute(srcl4, __float_as_int(s[r].y)));
    }
    // 2) (4,3): ctrl = lane bit 0, target = reg bit 3 (in-place cndmask swap)
    {
      bool ctrl = (lane & 1) != 0;
#pragma unroll
      for (int r = 0; r < 8; ++r) {
        int r1 = r | 8;
        v2 t0 = s[r], t1 = s[r1];
        s[r]  = ctrl ? t1 : t0;
        s[r1] = ctrl ? t0 : t1;
      }
    }
    // 3) (3,2)(2,1)(1,0): sequential in-place pair swaps (no temps)
    //    (3,2): swap (8,12)(9,13)(10,14)(11,15)
#pragma unroll
    for (int r = 8; r < 12; ++r) { v2 t = s[r]; s[r] = s[r | 4]; s[r | 4] = t; }
    //    (2,1): swap (4,6)(5,7)(12,14)(13,15)
    {
      const int rs[4] = {4, 5, 12, 13};
#pragma unroll
      for (int k = 0; k < 4; ++k) {
        int r = rs[k];
        v2 t = s[r]; s[r] = s[r | 2]; s[r | 2] = t;
      }
    }
    //    (1,0): swap (2,3)(6,7)(10,11)(14,15)
#pragma unroll
    for (int r = 2; r < 16; r += 4) { v2 t = s[r]; s[r] = s[r | 1]; s[r | 1] = t; }
    // 4) (0,9): ctrl = reg bit 0, target = lane bit 5 -> full exchange on odd r
#pragma unroll
    for (int r = 1; r < 16; r += 2) s[r] = shfl_xor_v2(s[r], 32);
  }

  // Measurement: out[b][q] = sum_idx prob[idx] * (bit(9-q) ? -1 : +1)
  float prob[16];
  float total = 0.0f;
#pragma unroll
  for (int r = 0; r < 16; ++r) {
    prob[r] = s[r].x * s[r].x + s[r].y * s[r].y;
    total += prob[r];
  }
  float part[10];
#pragma unroll
  for (int p = 0; p < 4; ++p) {
    float acc = 0.0f;
#pragma unroll
    for (int r = 0; r < 16; ++r)
      acc += (r & (1 << p)) ? -prob[r] : prob[r];
    part[p] = acc;
  }
#pragma unroll
  for (int p = 4; p < 10; ++p)
    part[p] = (lane & (1 << (p - 4))) ? -total : total;

#pragma unroll
  for (int p = 0; p < 10; ++p) {
#pragma unroll
    for (int m = 1; m < 64; m <<= 1)
      part[p] += __shfl_xor(part[p], m, 64);
  }

  if (lane == 0) {
#pragma unroll
    for (int q = 0; q < NQ; ++q)
      out[b * NQ + q] = part[9 - q];
  }
}

}  // namespace

extern "C" void kernel_launch(void* const* d_in, const int* in_sizes, int n_in,
                              void* d_out, int out_size, void* d_ws, size_t ws_size,
                              hipStream_t stream) {
  const float* x = (const float*)d_in[0];
  const float* w = (const float*)d_in[1];
  float* out = (float*)d_out;
  int batch = in_sizes[0] / NQ;
  int blocks = (batch + 3) / 4;  // 4 waves/block, 1 batch element per wave
  qsim<<<blocks, 256, 0, stream>>>(x, w, out, batch);
}

// Round 8
// 170.507 us; speedup vs baseline: 3.1789x; 1.4210x over previous
//
#include <hip/hip_runtime.h>
#include <math.h>

namespace {

constexpr int NQ = 10;
constexpr int NL = 4;
constexpr float PI_F = 3.14159265358979323846f;

// One batch element per wave. Each amp's (re,im) packed in ONE float2 ->
// state = 16 v2 = 32 VGPRs. Complex mul via v_pk_fma_f32 op_sel/neg_lo.
// Lane-exchange gates use DPP (VALU pipe) for xor masks 1,2,8; ds_swizzle
// for 4,16; ds_permute for 32. The trailing C(9->0) CNOT of each layer is
// DEFERRED into the next layer's wire-0 gate (same xor-32 pairing) — zero
// extra DS; measurement fixes the final pending swap via totE-totO on q=0.

typedef float v2 __attribute__((ext_vector_type(2)));

__device__ __forceinline__ float readlane_f(float v, int lane_const) {
  return __int_as_float(__builtin_amdgcn_readlane(__float_as_int(v), lane_const));
}

// xor-lane exchange: DPP where possible (masks 1,2,8), else DS.
template<int MASK>
__device__ __forceinline__ float lxor(float v) {
  if constexpr (MASK == 1 || MASK == 2 || MASK == 8) {
    constexpr int ctrl = (MASK == 1) ? 0xB1 : (MASK == 2) ? 0x4E : 0x128;
    int i = __float_as_int(v);
    return __int_as_float(__builtin_amdgcn_update_dpp(i, i, ctrl, 0xF, 0xF, true));
  } else {
    return __shfl_xor(v, MASK, 64);
  }
}
template<int MASK>
__device__ __forceinline__ v2 lxor2(v2 v) {
  v2 r; r.x = lxor<MASK>(v.x); r.y = lxor<MASK>(v.y); return r;
}

// d = u (*) a   (complex multiply; packed {re,im})
__device__ __forceinline__ v2 cmul(v2 u, v2 a) {
  v2 d;
  asm("v_pk_mul_f32 %0, %1, %2 op_sel:[0,0] op_sel_hi:[0,1]\n\t"
      "v_pk_fma_f32 %0, %1, %2, %0 op_sel:[1,1,0] op_sel_hi:[1,0,1] neg_lo:[1,0,0]"
      : "=&v"(d) : "v"(u), "v"(a));
  return d;
}
// d = acc + u (*) a
__device__ __forceinline__ v2 cfma(v2 u, v2 a, v2 acc) {
  v2 d;
  asm("v_pk_fma_f32 %0, %1, %2, %3 op_sel:[0,0,0] op_sel_hi:[0,1,1]\n\t"
      "v_pk_fma_f32 %0, %1, %2, %0 op_sel:[1,1,0] op_sel_hi:[1,0,1] neg_lo:[1,0,0]"
      : "=&v"(d) : "v"(u), "v"(a), "v"(acc));
  return d;
}

// Gate on state bit P. SWAP_ODD: a pending xor-32 lane swap on odd regs is
// consumed here (only legal for P==9, mask 32): odd regs swap own/partner
// coefficient roles, leaving a clean layout.
template<int P, bool SWAP_ODD>
__device__ __forceinline__ void apply_u(v2 (&s)[16],
                                        v2 u00, v2 u01, v2 u10, v2 u11,
                                        int lane) {
  if constexpr (P < 4) {
    constexpr int bit = 1 << P;
#pragma unroll
    for (int r = 0; r < 16; ++r) {
      if ((r & bit) == 0) {
        int r1 = r | bit;
        v2 a0 = s[r], a1 = s[r1];
        s[r]  = cfma(u01, a1, cmul(u00, a0));
        s[r1] = cfma(u11, a1, cmul(u10, a0));
      }
    }
  } else {
    constexpr int mask = 1 << (P - 4);
    bool hi = (lane & mask) != 0;
    v2 cA = hi ? u11 : u00;   // own coefficient (clean layout)
    v2 cB = hi ? u10 : u01;   // partner coefficient
#pragma unroll
    for (int r = 0; r < 16; ++r) {
      v2 p = lxor2<mask>(s[r]);
      if constexpr (SWAP_ODD) {
        if (r & 1) { s[r] = cfma(cA, p, cmul(cB, s[r])); continue; }
      }
      s[r] = cfma(cB, p, cmul(cA, s[r]));
    }
  }
}

template<int L, bool PEND>
__device__ __forceinline__ void layer(v2 (&s)[16], const float4* wmat,
                                      float cxv, float sxv, int lane, int srcl4) {
#define FUSED(i, SW) { \
    float4 wa = wmat[(L * NQ + (i)) * 2], wb = wmat[(L * NQ + (i)) * 2 + 1]; \
    float ca = readlane_f(cxv, (i)); \
    float sa = readlane_f(sxv, (i)); \
    v2 wa0 = {wa.x, wa.y}, wa1 = {wa.z, wa.w}; \
    v2 wb0 = {wb.x, wb.y}, wb1 = {wb.z, wb.w}; \
    v2 u00 = ca * wa0 + sa * wa1, u01 = ca * wa1 - sa * wa0; \
    v2 u10 = ca * wb0 + sa * wb1, u11 = ca * wb1 - sa * wb0; \
    apply_u<9 - (i), SW>(s, u00, u01, u10, u11, lane); }
  FUSED(0, PEND)            // wire0 = bit9 = lane xor 32; consumes pending swap
  FUSED(1, false) FUSED(2, false) FUSED(3, false) FUSED(4, false)
  FUSED(5, false) FUSED(6, false) FUSED(7, false) FUSED(8, false) FUSED(9, false)
#undef FUSED

  // CNOT chain: (9,8)(8,7)(7,6)(6,5)(5,4) as ONE composed bpermute
#pragma unroll
  for (int r = 0; r < 16; ++r) {
    s[r].x = __int_as_float(__builtin_amdgcn_ds_bpermute(srcl4, __float_as_int(s[r].x)));
    s[r].y = __int_as_float(__builtin_amdgcn_ds_bpermute(srcl4, __float_as_int(s[r].y)));
  }
  // (4,3): ctrl = lane bit 0, target = reg bit 3 (in-place cndmask swap)
  {
    bool ctrl = (lane & 1) != 0;
#pragma unroll
    for (int r = 0; r < 8; ++r) {
      int r1 = r | 8;
      v2 t0 = s[r], t1 = s[r1];
      s[r]  = ctrl ? t1 : t0;
      s[r1] = ctrl ? t0 : t1;
    }
  }
  // (3,2)(2,1)(1,0): sequential in-place pair swaps
#pragma unroll
  for (int r = 8; r < 12; ++r) { v2 t = s[r]; s[r] = s[r | 4]; s[r | 4] = t; }
  {
    const int rs[4] = {4, 5, 12, 13};
#pragma unroll
    for (int k = 0; k < 4; ++k) {
      int r = rs[k];
      v2 t = s[r]; s[r] = s[r | 2]; s[r | 2] = t;
    }
  }
#pragma unroll
  for (int r = 2; r < 16; r += 4) { v2 t = s[r]; s[r] = s[r | 1]; s[r | 1] = t; }
  // (0,9) CNOT (xor-32 on odd regs): DEFERRED to next layer / measurement.
}

__global__ __launch_bounds__(256, 6) void qsim(const float* __restrict__ x,
                                               const float* __restrict__ w,
                                               float* __restrict__ out, int batch) {
  // Batch-shared fused weight matrices W = RZ(w2)*RY(w1)*RZ(w0).
  __shared__ float4 wmat[NL * NQ * 2];
  int tid = threadIdx.x;
  if (tid < NL * NQ) {
    const float* wp = &w[tid * 3];
    float t0 = 0.5f * wp[0], t1 = 0.5f * wp[1], t2 = 0.5f * wp[2];
    float c1, s1; sincosf(t1, &s1, &c1);
    float cA, sA; sincosf(t0 + t2, &sA, &cA);
    float cB, sB; sincosf(t0 - t2, &sB, &cB);
    wmat[tid * 2]     = make_float4(c1 * cA, -c1 * sA, -s1 * cB, -s1 * sB);
    wmat[tid * 2 + 1] = make_float4(s1 * cB, -s1 * sB,  c1 * cA,  c1 * sA);
  }
  __syncthreads();

  int lane = tid & 63;
  int b = blockIdx.x * 4 + (tid >> 6);
  if (b >= batch) return;

  float cxv = 1.0f, sxv = 0.0f;
  if (lane < NQ) {
    float th = tanhf(x[b * NQ + lane]) * PI_F;
    sincosf(0.5f * th, &sxv, &cxv);
  }

  // Composed lane-permutation for the 5 lane-lane CNOTs.
  int srcl4;
  {
    int t = lane;
    t ^= (t >> 1) & 1;
    t ^= ((t >> 2) & 1) << 1;
    t ^= ((t >> 3) & 1) << 2;
    t ^= ((t >> 4) & 1) << 3;
    t ^= ((t >> 5) & 1) << 4;
    srcl4 = t << 2;
  }

  v2 s[16];
#pragma unroll
  for (int r = 0; r < 16; ++r) s[r] = (v2)(0.0f);
  if (lane == 0) s[0].x = 1.0f;

  layer<0, false>(s, wmat, cxv, sxv, lane, srcl4);
  layer<1, true >(s, wmat, cxv, sxv, lane, srcl4);
  layer<2, true >(s, wmat, cxv, sxv, lane, srcl4);
  layer<3, true >(s, wmat, cxv, sxv, lane, srcl4);
  // Layer 3's (0,9) is still pending: odd regs' amps live at lane^32.

  // Measurement. Lane permutation doesn't change per-reg sums except the
  // q=0 (lane bit 5) sign, which flips for odd regs -> use totE - totO there.
  float prob[16];
  float totE = 0.0f, totO = 0.0f;
#pragma unroll
  for (int r = 0; r < 16; ++r) {
    prob[r] = s[r].x * s[r].x + s[r].y * s[r].y;
    if (r & 1) totO += prob[r]; else totE += prob[r];
  }
  float total = totE + totO;
  float part[10];
#pragma unroll
  for (int p = 0; p < 4; ++p) {
    float acc = 0.0f;
#pragma unroll
    for (int r = 0; r < 16; ++r)
      acc += (r & (1 << p)) ? -prob[r] : prob[r];
    part[p] = acc;
  }
#pragma unroll
  for (int p = 4; p < 9; ++p)
    part[p] = (lane & (1 << (p - 4))) ? -total : total;
  {
    float d = totE - totO;             // pending xor-32 on odd regs
    part[9] = (lane & 32) ? -d : d;
  }

#pragma unroll
  for (int p = 0; p < 10; ++p) {
    float a = part[p];
    a += lxor<1>(a);
    a += lxor<2>(a);
    a += lxor<4>(a);
    a += lxor<8>(a);
    a += lxor<16>(a);
    a += lxor<32>(a);
    part[p] = a;
  }

  if (lane == 0) {
#pragma unroll
    for (int q = 0; q < NQ; ++q)
      out[b * NQ + q] = part[9 - q];
  }
}

}  // namespace

extern "C" void kernel_launch(void* const* d_in, const int* in_sizes, int n_in,
                              void* d_out, int out_size, void* d_ws, size_t ws_size,
                              hipStream_t stream) {
  const float* x = (const float*)d_in[0];
  const float* w = (const float*)d_in[1];
  float* out = (float*)d_out;
  int batch = in_sizes[0] / NQ;
  int blocks = (batch + 3) / 4;  // 4 waves/block, 1 batch element per wave
  qsim<<<blocks, 256, 0, stream>>>(x, w, out, batch);
}